// Round 12
// baseline (84.979 us; speedup 1.0000x reference)
//
#include <hip/hip_runtime.h>

#define BN 64
#define TN 1024
#define VN 1024
#define UNITSN 512
#define TWO_PI 6.283185307179586476925286766559f

typedef __attribute__((ext_vector_type(4))) float f32x4;

// K1: s[b*1024+tau] = sum_v x[b, tau, v].  One wave (64 lanes) per row of 1024
// floats, nontemporal loads (256MB never-reused stream; skip L2 alloc).
// (R11 measured-best — locked.)
__global__ void k_reduce_v(const float* __restrict__ x, float* __restrict__ s) {
    int row  = blockIdx.x * 4 + (threadIdx.x >> 6);   // 4 waves per 256-thread block
    int lane = threadIdx.x & 63;
    const f32x4* xr = reinterpret_cast<const f32x4*>(x) + (size_t)row * (VN / 4);
    float acc = 0.f;
#pragma unroll
    for (int i = 0; i < 4; ++i) {
        f32x4 v = __builtin_nontemporal_load(&xr[i * 64 + lane]);
        acc += (v.x + v.y) + (v.z + v.w);
    }
#pragma unroll
    for (int off = 32; off > 0; off >>= 1)
        acc += __shfl_down(acc, off, 64);
    if (lane == 0) s[row] = acc;
}

// K2: F[k*512+t] = sum_tau s[k,tau] * e^{-2*pi*i*tau*t/1024}, t in [0,512)
// One WAVE per (k,t); twiddle from integer phase via hw v_sin/v_cos.  (R5/R11 exact.)
__global__ void k_dft(const float* __restrict__ s, float2* __restrict__ F) {
    int w    = (blockIdx.x * blockDim.x + threadIdx.x) >> 6;  // global wave id
    int lane = threadIdx.x & 63;
    int b    = w >> 9;
    int t    = w & 511;
    const float* sb = s + b * TN;

    int p  = (lane * t) & 1023;        // phase index tau*t mod 1024
    int st = (64 * t) & 1023;          // per-step phase increment

    float ar = 0.f, ai = 0.f;
#pragma unroll
    for (int i = 0; i < 16; ++i) {
        float sv  = sb[lane + 64 * i];
        float ang = (float)p * (-TWO_PI / 1024.0f);
        float c   = __cosf(ang);
        float n   = __sinf(ang);
        ar = fmaf(sv, c, ar);
        ai = fmaf(sv, n, ai);
        p  = (p + st) & 1023;
    }
#pragma unroll
    for (int off = 32; off > 0; off >>= 1) {
        ar += __shfl_xor(ar, off, 64);
        ai += __shfl_xor(ai, off, 64);
    }
    if (lane == 0) F[b * UNITSN + t] = make_float2(ar, ai);
}

// K34: fused matmul + expand.  Block = (b, 32-j chunk); 1024 blocks, 4/CU.
// Phase 1: W[b,:] = (1/2048) * Bm[b,:] @ F  into LDS (each thread 2 t's,
//          coalesced F reads from L2; 512 FMA/thread).
// Phase 2: out[b][j][t][{re,im}] = W[b,t] + (t+j>=511 ? W[b,t+j-511] : 0),
//          W from LDS, stores byte-identical to R11's K4 (lane -> consecutive
//          float4, nontemporal).
__global__ void k_mm_expand(const float* __restrict__ Br, const float* __restrict__ Bi,
                            const float2* __restrict__ F, f32x4* __restrict__ out) {
    __shared__ float2 Wlds[UNITSN];
    int tid = threadIdx.x;
    int b   = blockIdx.x >> 4;
    int jc  = blockIdx.x & 15;

    // ---- phase 1: W row into LDS
    const float* brp = Br + b * 64;
    const float* bip = Bi + b * 64;
    float wra = 0.f, wia = 0.f, wrb = 0.f, wib = 0.f;
#pragma unroll 8
    for (int k = 0; k < 64; ++k) {
        float br = brp[k];                          // block-uniform -> scalar
        float bi = bip[k];
        float2 fa = F[k * UNITSN + tid];            // coalesced, L2-resident
        float2 fb = F[k * UNITSN + tid + 256];
        wra = fmaf(br, fa.x, wra); wra = fmaf(-bi, fa.y, wra);
        wia = fmaf(br, fa.y, wia); wia = fmaf(bi, fa.x, wia);
        wrb = fmaf(br, fb.x, wrb); wrb = fmaf(-bi, fb.y, wrb);
        wib = fmaf(br, fb.y, wib); wib = fmaf(bi, fb.x, wib);
    }
    const float coef = 1.0f / 2048.0f;
    Wlds[tid]       = make_float2(wra * coef, wia * coef);
    Wlds[tid + 256] = make_float2(wrb * coef, wib * coef);
    __syncthreads();

    // ---- phase 2: expand 32 j-rows
    size_t outBase = ((size_t)b << 17) + ((size_t)jc << 13);  // float4 units
#pragma unroll 4
    for (int it = 0; it < 32; ++it) {
        int j  = jc * 32 + it;
        int t2 = tid * 2;
        f32x4 w01 = *reinterpret_cast<const f32x4*>(&Wlds[t2]);  // 16B-aligned LDS
        int k0 = t2 + j - 511;
        float2 z0 = (k0 >= 0)     ? Wlds[k0]     : make_float2(0.f, 0.f);
        float2 z1 = (k0 + 1 >= 0) ? Wlds[k0 + 1] : make_float2(0.f, 0.f);
        f32x4 o = {w01.x + z0.x, w01.y + z0.y, w01.z + z1.x, w01.w + z1.y};
        __builtin_nontemporal_store(o, &out[outBase + ((size_t)it << 8) + tid]);
    }
}

extern "C" void kernel_launch(void* const* d_in, const int* in_sizes, int n_in,
                              void* d_out, int out_size, void* d_ws, size_t ws_size,
                              hipStream_t stream) {
    const float* x  = (const float*)d_in[0];
    // d_in[1], d_in[2] (A_r, A_i) are provably unused: the shift-register state's
    // column 0 stays zero for all 512 scan steps.
    const float* Br = (const float*)d_in[3];
    const float* Bi = (const float*)d_in[4];

    char* ws = (char*)d_ws;
    float*  s = (float*)ws;                       // 64*1024 f32 = 256 KB
    float2* F = (float2*)(ws + 256 * 1024);       // 64*512 cplx = 256 KB

    // K1: 65536 rows, 4 rows/block
    k_reduce_v<<<BN * TN / 4, 256, 0, stream>>>(x, s);
    // K2: 64 k * 512 t waves, 4 waves/block
    k_dft<<<(BN * UNITSN) / 4, 256, 0, stream>>>(s, F);
    // K34: 64 b * 16 j-chunks
    k_mm_expand<<<BN * 16, 256, 0, stream>>>(Br, Bi, F, (f32x4*)d_out);
}

// Round 13
// 79.794 us; speedup vs baseline: 1.0650x; 1.0650x over previous
//
#include <hip/hip_runtime.h>

#define BN 64
#define TN 1024
#define VN 1024
#define UNITSN 512
#define TWO_PI 6.283185307179586476925286766559f

typedef __attribute__((ext_vector_type(4))) float f32x4;

// K1: s[b*1024+tau] = sum_v x[b, tau, v].  One wave (64 lanes) per row of 1024
// floats, nontemporal loads (256MB never-reused stream; skip L2 alloc).
// (R11 measured-best — locked: NT isolated at -19.5us on R5 shapes.)
__global__ void k_reduce_v(const float* __restrict__ x, float* __restrict__ s) {
    int row  = blockIdx.x * 4 + (threadIdx.x >> 6);   // 4 waves per 256-thread block
    int lane = threadIdx.x & 63;
    const f32x4* xr = reinterpret_cast<const f32x4*>(x) + (size_t)row * (VN / 4);
    float acc = 0.f;
#pragma unroll
    for (int i = 0; i < 4; ++i) {
        f32x4 v = __builtin_nontemporal_load(&xr[i * 64 + lane]);
        acc += (v.x + v.y) + (v.z + v.w);
    }
#pragma unroll
    for (int off = 32; off > 0; off >>= 1)
        acc += __shfl_down(acc, off, 64);
    if (lane == 0) s[row] = acc;
}

// K2: F[b*512+t] = sum_tau s[b,tau] * e^{-2*pi*i*tau*t/1024}, t in [0,512)
// One WAVE per (b,t); twiddle from integer phase via hw v_sin/v_cos (full ILP,
// no serial rotation chain, no libm).  (R5/R11 measured-best middle.)
__global__ void k_dft(const float* __restrict__ s, float2* __restrict__ F) {
    int w    = (blockIdx.x * blockDim.x + threadIdx.x) >> 6;  // global wave id
    int lane = threadIdx.x & 63;
    int b    = w >> 9;
    int t    = w & 511;
    const float* sb = s + b * TN;

    int p  = (lane * t) & 1023;        // phase index tau*t mod 1024
    int st = (64 * t) & 1023;          // per-step phase increment

    float ar = 0.f, ai = 0.f;
#pragma unroll
    for (int i = 0; i < 16; ++i) {
        float sv  = sb[lane + 64 * i];
        float ang = (float)p * (-TWO_PI / 1024.0f);
        float c   = __cosf(ang);
        float n   = __sinf(ang);
        ar = fmaf(sv, c, ar);
        ai = fmaf(sv, n, ai);
        p  = (p + st) & 1023;
    }
#pragma unroll
    for (int off = 32; off > 0; off >>= 1) {
        ar += __shfl_xor(ar, off, 64);
        ai += __shfl_xor(ai, off, 64);
    }
    if (lane == 0) F[b * UNITSN + t] = make_float2(ar, ai);
}

// K3: W[b,t] = (1/2048) * sum_k (Br[b,k] + i*Bi[b,k]) * F[k,t]
// Wave = 16 t-values x 4 k-segments; shuffle-combine.  (R5/R11 exact.)
__global__ void k_matmul(const float* __restrict__ Br, const float* __restrict__ Bi,
                         const float2* __restrict__ F, float2* __restrict__ W) {
    int tid   = threadIdx.x;
    int lane  = tid & 63;
    int wv    = tid >> 6;
    int b     = blockIdx.x >> 3;
    int tbase = ((blockIdx.x & 7) * 4 + wv) * 16;
    int t     = tbase + (lane & 15);
    int seg   = lane >> 4;
    const float* brp = Br + b * 64 + seg * 16;
    const float* bip = Bi + b * 64 + seg * 16;
    float wr = 0.f, wi = 0.f;
#pragma unroll
    for (int i = 0; i < 16; ++i) {
        float br = brp[i];
        float bi = bip[i];
        float2 f = F[(seg * 16 + i) * UNITSN + t];
        wr = fmaf(br, f.x, wr); wr = fmaf(-bi, f.y, wr);
        wi = fmaf(br, f.y, wi); wi = fmaf(bi, f.x, wi);
    }
    wr += __shfl_xor(wr, 16, 64); wi += __shfl_xor(wi, 16, 64);
    wr += __shfl_xor(wr, 32, 64); wi += __shfl_xor(wi, 32, 64);
    if (seg == 0) {
        const float coef = 1.0f / 2048.0f;
        W[b * UNITSN + t] = make_float2(wr * coef, wi * coef);
    }
}

// K4: out[b][j][t][{re,im}] = W[b,t] + (t+j-511 >= 0 ? W[b, t+j-511] : 0)
// Thread writes 2 consecutive t's as one float4 (lanes -> consecutive 16B,
// perfect coalescing) + nontemporal store (134MB write-once stream).
// (R11 measured-best — locked.)
__global__ void k_expand(const float2* __restrict__ W, f32x4* __restrict__ out) {
    int idx = blockIdx.x * 256 + threadIdx.x;         // 64*512*256 total
    int t2 = (idx & 255) * 2;
    int j  = (idx >> 8) & 511;
    int b  = idx >> 17;
    const float2* Wb = W + b * UNITSN;
    const f32x4 w01 = *reinterpret_cast<const f32x4*>(Wb + t2);  // W[t2], W[t2+1]
    int k0 = t2 + j - 511;
    float2 z0 = (k0 >= 0)     ? Wb[k0]     : make_float2(0.f, 0.f);
    float2 z1 = (k0 + 1 >= 0) ? Wb[k0 + 1] : make_float2(0.f, 0.f);
    f32x4 o = {w01.x + z0.x, w01.y + z0.y, w01.z + z1.x, w01.w + z1.y};
    __builtin_nontemporal_store(o, &out[idx]);
}

extern "C" void kernel_launch(void* const* d_in, const int* in_sizes, int n_in,
                              void* d_out, int out_size, void* d_ws, size_t ws_size,
                              hipStream_t stream) {
    const float* x  = (const float*)d_in[0];
    // d_in[1], d_in[2] (A_r, A_i) are provably unused: the shift-register state's
    // column 0 stays zero for all 512 scan steps.
    const float* Br = (const float*)d_in[3];
    const float* Bi = (const float*)d_in[4];

    char* ws = (char*)d_ws;
    float*  s = (float*)ws;                       // 64*1024 f32 = 256 KB
    float2* F = (float2*)(ws + 256 * 1024);       // 64*512 cplx = 256 KB
    float2* W = (float2*)(ws + 512 * 1024);       // 64*512 cplx = 256 KB

    // K1: 65536 rows, 4 rows/block
    k_reduce_v<<<BN * TN / 4, 256, 0, stream>>>(x, s);
    // K2: 64 b * 512 t waves, 4 waves/block
    k_dft<<<(BN * UNITSN) / 4, 256, 0, stream>>>(s, F);
    // K3: 64 b * 8 t-chunks (wave = 16t x 4seg)
    k_matmul<<<BN * 8, 256, 0, stream>>>(Br, Bi, F, W);
    // K4: 64*512*256 threads
    k_expand<<<(BN * UNITSN * (UNITSN / 2)) / 256, 256, 0, stream>>>(W, (f32x4*)d_out);
}